// Round 6
// baseline (414.946 us; speedup 1.0000x reference)
//
#include <hip/hip_runtime.h>
#include <hip/hip_bf16.h>

// GaussianCodebook: out[b,s,c] = mean_d((x[b,s,d]-cb[d,c])^2)
//                 = x2[m] + c2[n] - (2/D) * dot(x[m,:], cb[:,n])
// B=8 S=4096 D=512 C=2048  -> GEMM M=32768 N=2048 K=512 (bf16 MFMA) + epilogue.
// R6: prep_x fused into GEMM. A is reg-staged (f32 global -> f2bf -> swizzled
//     ds_write_b128); x2 accumulated during staging (quad shfl reduce -> LDS).
//     B stays global_load_lds from bf16 cbT. T14 split: issue loads at
//     iter-top, gate AFTER MFMA, write buf(t+1) late. 3-deep LDS pipeline
//     (73KB -> 2 blocks/CU). Saves prep_x pass (~16us) + 64MB xb traffic.

typedef __attribute__((ext_vector_type(8))) short bf16x8;
typedef __attribute__((ext_vector_type(4))) float f32x4;

#define M_ROWS 32768
#define K_DIM  512
#define N_COLS 2048

__device__ __forceinline__ unsigned short f2bf(float f) {
    unsigned int u = __float_as_uint(f);
    return (unsigned short)((u + 0x7fffu + ((u >> 16) & 1u)) >> 16);  // RNE
}

__device__ __forceinline__ void gload_lds16(const void* g, void* l) {
    __builtin_amdgcn_global_load_lds(
        (const __attribute__((address_space(1))) unsigned int*)g,
        (__attribute__((address_space(3))) unsigned int*)l,
        16, 0, 0);
}

// ---- prep_cb: transpose cb [K=512][N=2048] f32 -> cbT [N][K] bf16, scaled by 2/D = 2^-8 ----
__global__ __launch_bounds__(256) void prep_cb_kernel(const float* __restrict__ cb,
                                                      unsigned short* __restrict__ cbT) {
    __shared__ float tile[32][65];
    const int k0 = blockIdx.x * 32;
    const int n0 = blockIdx.y * 64;
    const int tx = threadIdx.x & 63;
    const int ty = threadIdx.x >> 6;
    #pragma unroll
    for (int i = 0; i < 8; ++i) {
        const int k = ty + i * 4;
        tile[k][tx] = cb[(size_t)(k0 + k) * N_COLS + n0 + tx];
    }
    __syncthreads();
    const int kc = threadIdx.x & 31;
    const int nr = threadIdx.x >> 5;
    #pragma unroll
    for (int i = 0; i < 8; ++i) {
        const int n = nr + i * 8;
        cbT[(size_t)(n0 + n) * K_DIM + k0 + kc] = f2bf(tile[kc][n] * 0.00390625f);
    }
}

// ---- c2[n] = mean_k cb[k][n]^2 ----
__global__ __launch_bounds__(256) void c2_kernel(const float* __restrict__ cb,
                                                 float* __restrict__ c2) {
    __shared__ float p[4][64];
    const int t = threadIdx.x;
    const int nl = t & 63;
    const int kc = t >> 6;
    const int n = blockIdx.x * 64 + nl;
    float s = 0.0f;
    for (int k = kc * 128; k < kc * 128 + 128; ++k) {
        float v = cb[(size_t)k * N_COLS + n];
        s += v * v;
    }
    p[kc][nl] = s;
    __syncthreads();
    if (t < 64) {
        c2[blockIdx.x * 64 + t] =
            (p[0][t] + p[1][t] + p[2][t] + p[3][t]) * (1.0f / (float)K_DIM);
    }
}

// ======================= fused 128x256 GEMM =======================
// LDS buffer (shorts): A[128x32] @0 (4096 shorts), B[256x32] @4096 (8192 shorts)
// = 24KB; x3 = 72KB + 512B x2 staging.

__device__ __forceinline__ bf16x8 frag_ld(const unsigned short* h, int r, int lhi) {
    const int off = r * 32 + ((lhi ^ ((r >> 1) & 3)) << 3);
    return *reinterpret_cast<const bf16x8*>(&h[off]);
}

#define BAR()  do { asm volatile("" ::: "memory"); \
                    __builtin_amdgcn_s_barrier();  \
                    asm volatile("" ::: "memory"); } while (0)
#define GATE_(n) asm volatile("s_waitcnt vmcnt(" #n ")" ::: "memory")
#define GATE(n) GATE_(n)
#define LGKM0() asm volatile("s_waitcnt lgkmcnt(0)" ::: "memory")

__global__ __launch_bounds__(512, 4) void gemm_kernel(
        const float* __restrict__ X,            // [M][K] f32
        const unsigned short* __restrict__ Bt,  // [N][K] bf16 (scaled by 2^-8)
        const float* __restrict__ c2,
        float* __restrict__ out) {
    __shared__ unsigned short smem[3][12288];   // 72 KiB
    __shared__ float x2s[128];

    const int tid  = threadIdx.x;
    const int wid  = tid >> 6;
    const int lane = tid & 63;
    const int wr64 = (wid >> 2) * 64;       // 2 M-wave rows
    const int wc64 = (wid & 3) * 64;        // 4 N-wave cols
    const int l15 = lane & 15;
    const int lhi = lane >> 4;

    // T1: XCD-bijective swizzle; consecutive lbid within an XCD share the
    // same A m-panel across all 8 n-blocks (panel-major) -> L2 reuse.
    const int bid  = blockIdx.x;
    const int lbid = (bid & 7) * 256 + (bid >> 3);
    const int m0 = (lbid >> 3) * 128;
    const int n0 = (lbid & 7) * 256;

    // A reg-staging geometry: thread -> (row, k-chunk q of 8 floats).
    // LDS slot s must satisfy s ^ c(row) = q  (frag_ld inverts with ^c).
    const int arow = tid >> 2;               // 0..127
    const int aq   = tid & 3;                // k-chunk
    const int asl  = aq ^ ((arow >> 1) & 3);
    const int awchunk = (arow * 4 + asl) * 8;        // short index of 16B slot
    const float* Ab = X + (size_t)(m0 + arow) * K_DIM + aq * 8;

    const unsigned short* Bb = Bt + (size_t)n0 * K_DIM;
    const int o16b0 = wid * 64 + lane;
    const int rowb0 = o16b0 >> 2;
    const size_t boff0 = (size_t)rowb0 * K_DIM + (((o16b0 & 3) ^ ((rowb0 >> 1) & 3)) * 8);
    const int o16b1 = 512 + wid * 64 + lane;
    const int rowb1 = o16b1 >> 2;
    const size_t boff1 = (size_t)rowb1 * K_DIM + (((o16b1 & 3) ^ ((rowb1 >> 1) & 3)) * 8);

    f32x4 acc[4][4] = {};
    float4 rA[2][2];          // [parity][half] -- static-indexed after unroll
    float ss = 0.0f;

#define AISSUE(KT, P) do {                                                     \
    const float4* p_ = reinterpret_cast<const float4*>(Ab + (KT) * 32);        \
    rA[P][0] = p_[0]; rA[P][1] = p_[1]; } while (0)

#define BISSUE(KT, BUF) do {                                                   \
    gload_lds16(Bb + boff0 + (KT) * 32, &smem[(BUF)][4096 + wid * 512]);       \
    gload_lds16(Bb + boff1 + (KT) * 32, &smem[(BUF)][8192 + wid * 512]); } while (0)

#define AWRITE(BUF, P) do {                                                    \
    union { unsigned short us[8]; bf16x8 v8; } u_;                             \
    u_.us[0] = f2bf(rA[P][0].x); u_.us[1] = f2bf(rA[P][0].y);                  \
    u_.us[2] = f2bf(rA[P][0].z); u_.us[3] = f2bf(rA[P][0].w);                  \
    u_.us[4] = f2bf(rA[P][1].x); u_.us[5] = f2bf(rA[P][1].y);                  \
    u_.us[6] = f2bf(rA[P][1].z); u_.us[7] = f2bf(rA[P][1].w);                  \
    ss += rA[P][0].x * rA[P][0].x + rA[P][0].y * rA[P][0].y                    \
        + rA[P][0].z * rA[P][0].z + rA[P][0].w * rA[P][0].w                    \
        + rA[P][1].x * rA[P][1].x + rA[P][1].y * rA[P][1].y                    \
        + rA[P][1].z * rA[P][1].z + rA[P][1].w * rA[P][1].w;                   \
    *reinterpret_cast<bf16x8*>(&smem[(BUF)][awchunk]) = u_.v8; } while (0)

    // prologue: tiles 0,1 in flight; gate(4) -> A(0)+B(0) landed; write buf0.
    AISSUE(0, 0);
    BISSUE(0, 0);
    AISSUE(1, 1);
    BISSUE(1, 1);
    GATE(4);
    AWRITE(0, 0);
    LGKM0();
    BAR();

    #pragma unroll
    for (int t = 0; t < 16; ++t) {
        if (t < 14) { AISSUE(t + 2, t & 1); BISSUE(t + 2, (t + 2) % 3); }
        const unsigned short* cbuf = smem[t % 3];
        bf16x8 a[4], b[4];
        #pragma unroll
        for (int mf = 0; mf < 4; ++mf)
            a[mf] = frag_ld(cbuf, wr64 + mf * 16 + l15, lhi);
        #pragma unroll
        for (int nf = 0; nf < 4; ++nf)
            b[nf] = frag_ld(cbuf + 4096, wc64 + nf * 16 + l15, lhi);
        __builtin_amdgcn_s_setprio(1);
        #pragma unroll
        for (int mf = 0; mf < 4; ++mf)
            #pragma unroll
            for (int nf = 0; nf < 4; ++nf)
                acc[mf][nf] = __builtin_amdgcn_mfma_f32_16x16x32_bf16(a[mf], b[nf], acc[mf][nf], 0, 0, 0);
        __builtin_amdgcn_s_setprio(0);
        // gate A(t+1)+B(t+1) (oldest 4; the 4 ops issued this iter stay in
        // flight -> never drained mid-loop), then cvt+write buf(t+1).
        if (t < 14) { GATE(4); } else if (t == 14) { GATE(0); }
        if (t < 15) { AWRITE((t + 1) % 3, (t + 1) & 1); }
        LGKM0();       // ds_write retired before any wave reads it next iter
        BAR();
    }
#undef AISSUE
#undef BISSUE
#undef AWRITE

    // x2[row] = mean of x^2: quad-reduce the per-thread partial (128 elems each)
    ss += __shfl_xor(ss, 1);
    ss += __shfl_xor(ss, 2);
    if (aq == 0) x2s[arow] = ss * (1.0f / (float)K_DIM);
    __syncthreads();

    // epilogue: C/D layout col = lane&15, row = (lane>>4)*4 + reg
    #pragma unroll
    for (int mf = 0; mf < 4; ++mf) {
        const int lrow = wr64 + mf * 16 + lhi * 4;
        const int mrow = m0 + lrow;
        const float xv0 = x2s[lrow + 0];
        const float xv1 = x2s[lrow + 1];
        const float xv2 = x2s[lrow + 2];
        const float xv3 = x2s[lrow + 3];
        #pragma unroll
        for (int nf = 0; nf < 4; ++nf) {
            const int col = n0 + wc64 + nf * 16 + l15;
            const float cv = c2[col];
            float* o = out + (size_t)mrow * N_COLS + col;
            o[0 * N_COLS] = xv0 + cv - acc[mf][nf][0];
            o[1 * N_COLS] = xv1 + cv - acc[mf][nf][1];
            o[2 * N_COLS] = xv2 + cv - acc[mf][nf][2];
            o[3 * N_COLS] = xv3 + cv - acc[mf][nf][3];
        }
    }
}

extern "C" void kernel_launch(void* const* d_in, const int* in_sizes, int n_in,
                              void* d_out, int out_size, void* d_ws, size_t ws_size,
                              hipStream_t stream) {
    const float* x  = (const float*)d_in[0];   // [8,4096,512]
    const float* cb = (const float*)d_in[1];   // [1,1,512,2048]
    float* out = (float*)d_out;                // [8,4096,2048]

    char* ws = (char*)d_ws;
    unsigned short* cbT = (unsigned short*)ws;                 // 2 MB
    float* c2 = (float*)(ws + (size_t)2097152);                // 8 KB

    prep_cb_kernel<<<dim3(16, 32), 256, 0, stream>>>(cb, cbT);
    c2_kernel<<<N_COLS / 64, 256, 0, stream>>>(cb, c2);
    gemm_kernel<<<dim3((M_ROWS / 128) * (N_COLS / 256)), 512, 0, stream>>>(x, cbT, c2, out);
}

// Round 7
// 334.192 us; speedup vs baseline: 1.2416x; 1.2416x over previous
//
#include <hip/hip_runtime.h>
#include <hip/hip_bf16.h>

// GaussianCodebook: out[b,s,c] = mean_d((x[b,s,d]-cb[d,c])^2)
//                 = x2[m] + c2[n] - (2/D) * dot(x[m,:], cb[:,n])
// B=8 S=4096 D=512 C=2048  -> GEMM M=32768 N=2048 K=512 (bf16 MFMA) + epilogue.
// R7 (= R6 fixed): fused prep_x, but with (a) 16 macro-expanded STEPs so every
//     buffer/parity index is a literal (R6's rolled loop -> runtime-indexed
//     rA -> scratch spill: VGPR 64, +630MB scratch writes), and (b) A-loads
//     pipelined only 1 tile ahead (single rAlo/rAhi, 8 VGPR) to stay under
//     the 128-VGPR cap at 2 blocks/CU. Gates: issue order A(t+1),B(t+2);
//     GATE(2) after MFMA drains A(t+1)+B(t+1), leaves B(t+2) in flight.

typedef __attribute__((ext_vector_type(8))) short bf16x8;
typedef __attribute__((ext_vector_type(4))) float f32x4;

#define M_ROWS 32768
#define K_DIM  512
#define N_COLS 2048

__device__ __forceinline__ unsigned short f2bf(float f) {
    unsigned int u = __float_as_uint(f);
    return (unsigned short)((u + 0x7fffu + ((u >> 16) & 1u)) >> 16);  // RNE
}

__device__ __forceinline__ void gload_lds16(const void* g, void* l) {
    __builtin_amdgcn_global_load_lds(
        (const __attribute__((address_space(1))) unsigned int*)g,
        (__attribute__((address_space(3))) unsigned int*)l,
        16, 0, 0);
}

// ---- prep_cb: transpose cb [K=512][N=2048] f32 -> cbT [N][K] bf16, scaled by 2/D = 2^-8 ----
__global__ __launch_bounds__(256) void prep_cb_kernel(const float* __restrict__ cb,
                                                      unsigned short* __restrict__ cbT) {
    __shared__ float tile[32][65];
    const int k0 = blockIdx.x * 32;
    const int n0 = blockIdx.y * 64;
    const int tx = threadIdx.x & 63;
    const int ty = threadIdx.x >> 6;
    #pragma unroll
    for (int i = 0; i < 8; ++i) {
        const int k = ty + i * 4;
        tile[k][tx] = cb[(size_t)(k0 + k) * N_COLS + n0 + tx];
    }
    __syncthreads();
    const int kc = threadIdx.x & 31;
    const int nr = threadIdx.x >> 5;
    #pragma unroll
    for (int i = 0; i < 8; ++i) {
        const int n = nr + i * 8;
        cbT[(size_t)(n0 + n) * K_DIM + k0 + kc] = f2bf(tile[kc][n] * 0.00390625f);
    }
}

// ---- c2[n] = mean_k cb[k][n]^2 ----
__global__ __launch_bounds__(256) void c2_kernel(const float* __restrict__ cb,
                                                 float* __restrict__ c2) {
    __shared__ float p[4][64];
    const int t = threadIdx.x;
    const int nl = t & 63;
    const int kc = t >> 6;
    const int n = blockIdx.x * 64 + nl;
    float s = 0.0f;
    for (int k = kc * 128; k < kc * 128 + 128; ++k) {
        float v = cb[(size_t)k * N_COLS + n];
        s += v * v;
    }
    p[kc][nl] = s;
    __syncthreads();
    if (t < 64) {
        c2[blockIdx.x * 64 + t] =
            (p[0][t] + p[1][t] + p[2][t] + p[3][t]) * (1.0f / (float)K_DIM);
    }
}

// ======================= fused 128x256 GEMM =======================
// LDS buffer (shorts): A[128x32] @0 (4096 shorts), B[256x32] @4096 (8192 shorts)
// = 24KB; x3 = 72KB (+512B x2s).

__device__ __forceinline__ bf16x8 frag_ld(const unsigned short* h, int r, int lhi) {
    const int off = r * 32 + ((lhi ^ ((r >> 1) & 3)) << 3);
    return *reinterpret_cast<const bf16x8*>(&h[off]);
}

#define BAR()  do { asm volatile("" ::: "memory"); \
                    __builtin_amdgcn_s_barrier();  \
                    asm volatile("" ::: "memory"); } while (0)
#define GATE_(n) asm volatile("s_waitcnt vmcnt(" #n ")" ::: "memory")
#define GATE(n) GATE_(n)
#define LGKM0() asm volatile("s_waitcnt lgkmcnt(0)" ::: "memory")

__global__ __launch_bounds__(512, 4) void gemm_kernel(
        const float* __restrict__ X,            // [M][K] f32
        const unsigned short* __restrict__ Bt,  // [N][K] bf16 (scaled by 2^-8)
        const float* __restrict__ c2,
        float* __restrict__ out) {
    __shared__ unsigned short smem[3][12288];   // 72 KiB
    __shared__ float x2s[128];

    const int tid  = threadIdx.x;
    const int wid  = tid >> 6;
    const int lane = tid & 63;
    const int wr64 = (wid >> 2) * 64;       // 2 M-wave rows
    const int wc64 = (wid & 3) * 64;        // 4 N-wave cols
    const int l15 = lane & 15;
    const int lhi = lane >> 4;

    // T1: XCD-bijective swizzle; the 8 n-blocks of one m-panel land on the
    // same XCD consecutively -> A panel reused from L2; all of B (2MB) fits L2.
    const int bid  = blockIdx.x;
    const int lbid = (bid & 7) * 256 + (bid >> 3);
    const int m0 = (lbid >> 3) * 128;
    const int n0 = (lbid & 7) * 256;

    // A reg-staging geometry: thread -> (row, k-chunk q of 8 floats).
    // Written LDS slot s = q ^ c(row) (frag_ld inverts with ^c(row)).
    const int arow = tid >> 2;               // 0..127
    const int aq   = tid & 3;                // k-chunk
    const int asl  = aq ^ ((arow >> 1) & 3);
    const int awchunk = (arow * 4 + asl) * 8;        // short index of 16B slot
    const float* Ab = X + (size_t)(m0 + arow) * K_DIM + aq * 8;

    const unsigned short* Bb = Bt + (size_t)n0 * K_DIM;
    const int o16b0 = wid * 64 + lane;
    const int rowb0 = o16b0 >> 2;
    const size_t boff0 = (size_t)rowb0 * K_DIM + (((o16b0 & 3) ^ ((rowb0 >> 1) & 3)) * 8);
    const int o16b1 = 512 + wid * 64 + lane;
    const int rowb1 = o16b1 >> 2;
    const size_t boff1 = (size_t)rowb1 * K_DIM + (((o16b1 & 3) ^ ((rowb1 >> 1) & 3)) * 8);

    f32x4 acc[4][4] = {};
    float4 rAlo, rAhi;        // single in-flight A chunk (named, never indexed)
    float ss = 0.0f;

#define AISSUE(KT) do {                                                        \
    const float4* p_ = reinterpret_cast<const float4*>(Ab + (KT) * 32);        \
    rAlo = p_[0]; rAhi = p_[1]; } while (0)

#define BISSUE(KT, BUF) do {                                                   \
    gload_lds16(Bb + boff0 + (KT) * 32, &smem[(BUF)][4096 + wid * 512]);       \
    gload_lds16(Bb + boff1 + (KT) * 32, &smem[(BUF)][8192 + wid * 512]); } while (0)

#define AWRITE(BUF) do {                                                       \
    union { unsigned short us[8]; bf16x8 v8; } u_;                             \
    u_.us[0] = f2bf(rAlo.x); u_.us[1] = f2bf(rAlo.y);                          \
    u_.us[2] = f2bf(rAlo.z); u_.us[3] = f2bf(rAlo.w);                          \
    u_.us[4] = f2bf(rAhi.x); u_.us[5] = f2bf(rAhi.y);                          \
    u_.us[6] = f2bf(rAhi.z); u_.us[7] = f2bf(rAhi.w);                          \
    ss += rAlo.x * rAlo.x + rAlo.y * rAlo.y + rAlo.z * rAlo.z + rAlo.w * rAlo.w\
        + rAhi.x * rAhi.x + rAhi.y * rAhi.y + rAhi.z * rAhi.z + rAhi.w * rAhi.w;\
    *reinterpret_cast<bf16x8*>(&smem[(BUF)][awchunk]) = u_.v8; } while (0)

#define STEP(T)                                                                \
  {                                                                            \
    if ((T) < 15) AISSUE((T) + 1);                                             \
    if ((T) < 14) BISSUE((T) + 2, ((T) + 2) % 3);                              \
    const unsigned short* cbuf = smem[(T) % 3];                                \
    bf16x8 a[4], b[4];                                                         \
    _Pragma("unroll")                                                          \
    for (int mf = 0; mf < 4; ++mf)                                             \
        a[mf] = frag_ld(cbuf, wr64 + mf * 16 + l15, lhi);                      \
    _Pragma("unroll")                                                          \
    for (int nf = 0; nf < 4; ++nf)                                             \
        b[nf] = frag_ld(cbuf + 4096, wc64 + nf * 16 + l15, lhi);               \
    __builtin_amdgcn_s_setprio(1);                                             \
    _Pragma("unroll")                                                          \
    for (int mf = 0; mf < 4; ++mf)                                             \
        _Pragma("unroll")                                                      \
        for (int nf = 0; nf < 4; ++nf)                                         \
            acc[mf][nf] = __builtin_amdgcn_mfma_f32_16x16x32_bf16(a[mf], b[nf], acc[mf][nf], 0, 0, 0); \
    __builtin_amdgcn_s_setprio(0);                                             \
    if ((T) < 14) { GATE(2); } else if ((T) == 14) { GATE(0); }                \
    if ((T) < 15) { AWRITE(((T) + 1) % 3); LGKM0(); BAR(); }                   \
  }

    // prologue: A(0)->regs, B(0)->buf0, B(1)->buf1; gate leaves B(1) in flight
    AISSUE(0);
    BISSUE(0, 0);
    BISSUE(1, 1);
    GATE(2);
    AWRITE(0);
    LGKM0();
    BAR();

    STEP(0)  STEP(1)  STEP(2)  STEP(3)
    STEP(4)  STEP(5)  STEP(6)  STEP(7)
    STEP(8)  STEP(9)  STEP(10) STEP(11)
    STEP(12) STEP(13) STEP(14) STEP(15)

#undef AISSUE
#undef BISSUE
#undef AWRITE
#undef STEP

    // x2[row] = mean_k x^2: quad-reduce per-thread partial (128 elems each)
    ss += __shfl_xor(ss, 1);
    ss += __shfl_xor(ss, 2);
    if (aq == 0) x2s[arow] = ss * (1.0f / (float)K_DIM);
    __syncthreads();

    // epilogue: C/D layout col = lane&15, row = (lane>>4)*4 + reg
    #pragma unroll
    for (int mf = 0; mf < 4; ++mf) {
        const int lrow = wr64 + mf * 16 + lhi * 4;
        const int mrow = m0 + lrow;
        const float xv0 = x2s[lrow + 0];
        const float xv1 = x2s[lrow + 1];
        const float xv2 = x2s[lrow + 2];
        const float xv3 = x2s[lrow + 3];
        #pragma unroll
        for (int nf = 0; nf < 4; ++nf) {
            const int col = n0 + wc64 + nf * 16 + l15;
            const float cv = c2[col];
            float* o = out + (size_t)mrow * N_COLS + col;
            o[0 * N_COLS] = xv0 + cv - acc[mf][nf][0];
            o[1 * N_COLS] = xv1 + cv - acc[mf][nf][1];
            o[2 * N_COLS] = xv2 + cv - acc[mf][nf][2];
            o[3 * N_COLS] = xv3 + cv - acc[mf][nf][3];
        }
    }
}

extern "C" void kernel_launch(void* const* d_in, const int* in_sizes, int n_in,
                              void* d_out, int out_size, void* d_ws, size_t ws_size,
                              hipStream_t stream) {
    const float* x  = (const float*)d_in[0];   // [8,4096,512]
    const float* cb = (const float*)d_in[1];   // [1,1,512,2048]
    float* out = (float*)d_out;                // [8,4096,2048]

    char* ws = (char*)d_ws;
    unsigned short* cbT = (unsigned short*)ws;                 // 2 MB
    float* c2 = (float*)(ws + (size_t)2097152);                // 8 KB

    prep_cb_kernel<<<dim3(16, 32), 256, 0, stream>>>(cb, cbT);
    c2_kernel<<<N_COLS / 64, 256, 0, stream>>>(cb, c2);
    gemm_kernel<<<dim3((M_ROWS / 128) * (N_COLS / 256)), 512, 0, stream>>>(x, cbT, c2, out);
}

// Round 8
// 204.305 us; speedup vs baseline: 2.0310x; 1.6358x over previous
//
#include <hip/hip_runtime.h>
#include <hip/hip_bf16.h>

// GaussianCodebook: out[b,s,c] = mean_d((x[b,s,d]-cb[d,c])^2)
//                 = x2[m] + c2[n] - (2/D) * dot(x[m,:], cb[:,n])
// B=8 S=4096 D=512 C=2048  -> GEMM M=32768 N=2048 K=512 (bf16 MFMA) + epilogue.
// R8 (= R7 + spill fix): empirically this toolchain maps __launch_bounds__
//     (512,4) -> 64-VGPR cap (R6/R7: VGPR_Count=64, acc spilled, +450MB
//     scratch). (512,2) -> 128-VGPR cap (R4). Switch to (512,2) and load the
//     A-frag inside the mf loop (peak live ~107 VGPR < 128). LDS 72.5KB
//     still gives 2 blocks/CU.

typedef __attribute__((ext_vector_type(8))) short bf16x8;
typedef __attribute__((ext_vector_type(4))) float f32x4;

#define M_ROWS 32768
#define K_DIM  512
#define N_COLS 2048

__device__ __forceinline__ unsigned short f2bf(float f) {
    unsigned int u = __float_as_uint(f);
    return (unsigned short)((u + 0x7fffu + ((u >> 16) & 1u)) >> 16);  // RNE
}

__device__ __forceinline__ void gload_lds16(const void* g, void* l) {
    __builtin_amdgcn_global_load_lds(
        (const __attribute__((address_space(1))) unsigned int*)g,
        (__attribute__((address_space(3))) unsigned int*)l,
        16, 0, 0);
}

// ---- prep_cb: transpose cb [K=512][N=2048] f32 -> cbT [N][K] bf16, scaled by 2/D = 2^-8 ----
__global__ __launch_bounds__(256) void prep_cb_kernel(const float* __restrict__ cb,
                                                      unsigned short* __restrict__ cbT) {
    __shared__ float tile[32][65];
    const int k0 = blockIdx.x * 32;
    const int n0 = blockIdx.y * 64;
    const int tx = threadIdx.x & 63;
    const int ty = threadIdx.x >> 6;
    #pragma unroll
    for (int i = 0; i < 8; ++i) {
        const int k = ty + i * 4;
        tile[k][tx] = cb[(size_t)(k0 + k) * N_COLS + n0 + tx];
    }
    __syncthreads();
    const int kc = threadIdx.x & 31;
    const int nr = threadIdx.x >> 5;
    #pragma unroll
    for (int i = 0; i < 8; ++i) {
        const int n = nr + i * 8;
        cbT[(size_t)(n0 + n) * K_DIM + k0 + kc] = f2bf(tile[kc][n] * 0.00390625f);
    }
}

// ---- c2[n] = mean_k cb[k][n]^2 ----
__global__ __launch_bounds__(256) void c2_kernel(const float* __restrict__ cb,
                                                 float* __restrict__ c2) {
    __shared__ float p[4][64];
    const int t = threadIdx.x;
    const int nl = t & 63;
    const int kc = t >> 6;
    const int n = blockIdx.x * 64 + nl;
    float s = 0.0f;
    for (int k = kc * 128; k < kc * 128 + 128; ++k) {
        float v = cb[(size_t)k * N_COLS + n];
        s += v * v;
    }
    p[kc][nl] = s;
    __syncthreads();
    if (t < 64) {
        c2[blockIdx.x * 64 + t] =
            (p[0][t] + p[1][t] + p[2][t] + p[3][t]) * (1.0f / (float)K_DIM);
    }
}

// ======================= fused 128x256 GEMM =======================
// LDS buffer (shorts): A[128x32] @0 (4096 shorts), B[256x32] @4096 (8192 shorts)
// = 24KB; x3 = 72KB (+512B x2s).

__device__ __forceinline__ bf16x8 frag_ld(const unsigned short* h, int r, int lhi) {
    const int off = r * 32 + ((lhi ^ ((r >> 1) & 3)) << 3);
    return *reinterpret_cast<const bf16x8*>(&h[off]);
}

#define BAR()  do { asm volatile("" ::: "memory"); \
                    __builtin_amdgcn_s_barrier();  \
                    asm volatile("" ::: "memory"); } while (0)
#define GATE_(n) asm volatile("s_waitcnt vmcnt(" #n ")" ::: "memory")
#define GATE(n) GATE_(n)
#define LGKM0() asm volatile("s_waitcnt lgkmcnt(0)" ::: "memory")

__global__ __launch_bounds__(512, 2) void gemm_kernel(
        const float* __restrict__ X,            // [M][K] f32
        const unsigned short* __restrict__ Bt,  // [N][K] bf16 (scaled by 2^-8)
        const float* __restrict__ c2,
        float* __restrict__ out) {
    __shared__ unsigned short smem[3][12288];   // 72 KiB
    __shared__ float x2s[128];

    const int tid  = threadIdx.x;
    const int wid  = tid >> 6;
    const int lane = tid & 63;
    const int wr64 = (wid >> 2) * 64;       // 2 M-wave rows
    const int wc64 = (wid & 3) * 64;        // 4 N-wave cols
    const int l15 = lane & 15;
    const int lhi = lane >> 4;

    // T1: XCD-bijective swizzle; the 8 n-blocks of one m-panel land on the
    // same XCD consecutively -> A panel reused from L2; all of B (2MB) fits L2.
    const int bid  = blockIdx.x;
    const int lbid = (bid & 7) * 256 + (bid >> 3);
    const int m0 = (lbid >> 3) * 128;
    const int n0 = (lbid & 7) * 256;

    // A reg-staging geometry: thread -> (row, k-chunk q of 8 floats).
    // Written LDS slot s = q ^ c(row) (frag_ld inverts with ^c(row)).
    const int arow = tid >> 2;               // 0..127
    const int aq   = tid & 3;                // k-chunk
    const int asl  = aq ^ ((arow >> 1) & 3);
    const int awchunk = (arow * 4 + asl) * 8;        // short index of 16B slot
    const float* Ab = X + (size_t)(m0 + arow) * K_DIM + aq * 8;

    const unsigned short* Bb = Bt + (size_t)n0 * K_DIM;
    const int o16b0 = wid * 64 + lane;
    const int rowb0 = o16b0 >> 2;
    const size_t boff0 = (size_t)rowb0 * K_DIM + (((o16b0 & 3) ^ ((rowb0 >> 1) & 3)) * 8);
    const int o16b1 = 512 + wid * 64 + lane;
    const int rowb1 = o16b1 >> 2;
    const size_t boff1 = (size_t)rowb1 * K_DIM + (((o16b1 & 3) ^ ((rowb1 >> 1) & 3)) * 8);

    f32x4 acc[4][4] = {};
    float4 rAlo, rAhi;        // single in-flight A chunk (named, never indexed)
    float ss = 0.0f;

#define AISSUE(KT) do {                                                        \
    const float4* p_ = reinterpret_cast<const float4*>(Ab + (KT) * 32);        \
    rAlo = p_[0]; rAhi = p_[1]; } while (0)

#define BISSUE(KT, BUF) do {                                                   \
    gload_lds16(Bb + boff0 + (KT) * 32, &smem[(BUF)][4096 + wid * 512]);       \
    gload_lds16(Bb + boff1 + (KT) * 32, &smem[(BUF)][8192 + wid * 512]); } while (0)

#define AWRITE(BUF) do {                                                       \
    union { unsigned short us[8]; bf16x8 v8; } u_;                             \
    u_.us[0] = f2bf(rAlo.x); u_.us[1] = f2bf(rAlo.y);                          \
    u_.us[2] = f2bf(rAlo.z); u_.us[3] = f2bf(rAlo.w);                          \
    u_.us[4] = f2bf(rAhi.x); u_.us[5] = f2bf(rAhi.y);                          \
    u_.us[6] = f2bf(rAhi.z); u_.us[7] = f2bf(rAhi.w);                          \
    ss += rAlo.x * rAlo.x + rAlo.y * rAlo.y + rAlo.z * rAlo.z + rAlo.w * rAlo.w\
        + rAhi.x * rAhi.x + rAhi.y * rAhi.y + rAhi.z * rAhi.z + rAhi.w * rAhi.w;\
    *reinterpret_cast<bf16x8*>(&smem[(BUF)][awchunk]) = u_.v8; } while (0)

#define STEP(T)                                                                \
  {                                                                            \
    if ((T) < 15) AISSUE((T) + 1);                                             \
    if ((T) < 14) BISSUE((T) + 2, ((T) + 2) % 3);                              \
    const unsigned short* cbuf = smem[(T) % 3];                                \
    bf16x8 b[4];                                                               \
    _Pragma("unroll")                                                          \
    for (int nf = 0; nf < 4; ++nf)                                             \
        b[nf] = frag_ld(cbuf + 4096, wc64 + nf * 16 + l15, lhi);               \
    __builtin_amdgcn_s_setprio(1);                                             \
    _Pragma("unroll")                                                          \
    for (int mf = 0; mf < 4; ++mf) {                                           \
        const bf16x8 a = frag_ld(cbuf, wr64 + mf * 16 + l15, lhi);             \
        _Pragma("unroll")                                                      \
        for (int nf = 0; nf < 4; ++nf)                                         \
            acc[mf][nf] = __builtin_amdgcn_mfma_f32_16x16x32_bf16(a, b[nf], acc[mf][nf], 0, 0, 0); \
    }                                                                          \
    __builtin_amdgcn_s_setprio(0);                                             \
    if ((T) < 14) { GATE(2); } else if ((T) == 14) { GATE(0); }                \
    if ((T) < 15) { AWRITE(((T) + 1) % 3); LGKM0(); BAR(); }                   \
  }

    // prologue: A(0)->regs, B(0)->buf0, B(1)->buf1; gate leaves B(1) in flight
    AISSUE(0);
    BISSUE(0, 0);
    BISSUE(1, 1);
    GATE(2);
    AWRITE(0);
    LGKM0();
    BAR();

    STEP(0)  STEP(1)  STEP(2)  STEP(3)
    STEP(4)  STEP(5)  STEP(6)  STEP(7)
    STEP(8)  STEP(9)  STEP(10) STEP(11)
    STEP(12) STEP(13) STEP(14) STEP(15)

#undef AISSUE
#undef BISSUE
#undef AWRITE
#undef STEP

    // x2[row] = mean_k x^2: quad-reduce per-thread partial (128 elems each)
    ss += __shfl_xor(ss, 1);
    ss += __shfl_xor(ss, 2);
    if (aq == 0) x2s[arow] = ss * (1.0f / (float)K_DIM);
    __syncthreads();

    // epilogue: C/D layout col = lane&15, row = (lane>>4)*4 + reg
    #pragma unroll
    for (int mf = 0; mf < 4; ++mf) {
        const int lrow = wr64 + mf * 16 + lhi * 4;
        const int mrow = m0 + lrow;
        const float xv0 = x2s[lrow + 0];
        const float xv1 = x2s[lrow + 1];
        const float xv2 = x2s[lrow + 2];
        const float xv3 = x2s[lrow + 3];
        #pragma unroll
        for (int nf = 0; nf < 4; ++nf) {
            const int col = n0 + wc64 + nf * 16 + l15;
            const float cv = c2[col];
            float* o = out + (size_t)mrow * N_COLS + col;
            o[0 * N_COLS] = xv0 + cv - acc[mf][nf][0];
            o[1 * N_COLS] = xv1 + cv - acc[mf][nf][1];
            o[2 * N_COLS] = xv2 + cv - acc[mf][nf][2];
            o[3 * N_COLS] = xv3 + cv - acc[mf][nf][3];
        }
    }
}

extern "C" void kernel_launch(void* const* d_in, const int* in_sizes, int n_in,
                              void* d_out, int out_size, void* d_ws, size_t ws_size,
                              hipStream_t stream) {
    const float* x  = (const float*)d_in[0];   // [8,4096,512]
    const float* cb = (const float*)d_in[1];   // [1,1,512,2048]
    float* out = (float*)d_out;                // [8,4096,2048]

    char* ws = (char*)d_ws;
    unsigned short* cbT = (unsigned short*)ws;                 // 2 MB
    float* c2 = (float*)(ws + (size_t)2097152);                // 8 KB

    prep_cb_kernel<<<dim3(16, 32), 256, 0, stream>>>(cb, cbT);
    c2_kernel<<<N_COLS / 64, 256, 0, stream>>>(cb, c2);
    gemm_kernel<<<dim3((M_ROWS / 128) * (N_COLS / 256)), 512, 0, stream>>>(x, cbT, c2, out);
}